// Round 8
// baseline (356.703 us; speedup 1.0000x reference)
//
#include <hip/hip_runtime.h>
#include <math.h>

typedef __attribute__((ext_vector_type(4))) float f4;
typedef __attribute__((ext_vector_type(8))) short s8v;   // bf16x8 MFMA fragment
typedef __attribute__((ext_vector_type(4))) unsigned int u4v;
typedef __attribute__((ext_vector_type(2))) unsigned int u2v;

#define NVOX 262144        // 64^3
#define MB_TOT 67108864    // 4*64*NVOX

__device__ __forceinline__ float sigm(float x){ return 1.0f/(1.0f+expf(-x)); }
__device__ __forceinline__ unsigned short f2b(float f){
  unsigned x = __float_as_uint(f);
  return (unsigned short)((x + 0x7fffu + ((x>>16)&1u)) >> 16);
}
__device__ __forceinline__ unsigned cvtpk(float lo, float hi){
  unsigned r;
  asm("v_cvt_pk_bf16_f32 %0, %1, %2" : "=v"(r) : "v"(lo), "v"(hi));
  return r;
}
__device__ __forceinline__ float bl(unsigned u){ return __uint_as_float(u<<16); }
__device__ __forceinline__ float bh(unsigned u){ return __uint_as_float(u & 0xffff0000u); }

// ---------------- pass 1: 512 blocks (half-planes), explicit load batches ----------------
// block = (mc = b>>1, seg = b&1 -> i in [seg*32, seg*32+32)).
// thread: chunk = tid&15 (z = chunk*4..+3), j = tid>>4. 2 blocks/CU = 32 waves/CU.
// Explicit 4-load batches keep >=4KB in flight per wave. 20 named scalar accumulators
// (static indexing; round-6 scratch lesson). Merge: LDS atomics -> global atomicAdd.

#define LD1(I) (*reinterpret_cast<const f4*>(xp + (size_t)((I)*64 + j)*64 + chunk*4))

#define BODY(I, V) { \
  float s_ = ((V).x+(V).y)+((V).z+(V).w); \
  float wB_ = (V).x*wqz0 + (V).y*wqz1 + (V).z*wqz2 + (V).w*wqz3; \
  float wA_ = s_ - wB_; \
  if (((I)>>4)==0) b0 += s_; else if (((I)>>4)==1) b1 += s_; \
  else if (((I)>>4)==2) b2 += s_; else b3 += s_; \
  const int   li_  = ((I)<8)?0:(((I)>=56)?3:(((I)-8)>>4)); \
  const float wi_  = ((I)<8||(I)>=56)?0.0f:(((I)+0.5f)*0.0625f-0.5f-(float)li_); \
  const float h0_ = (li_==0)?(1.0f-wi_):0.0f; \
  const float h1_ = (li_==1)?(1.0f-wi_):((li_==0)?wi_:0.0f); \
  const float h2_ = (li_==2)?(1.0f-wi_):((li_==1)?wi_:0.0f); \
  const float h3_ = (li_==3)?(1.0f-wi_):((li_==2)?wi_:0.0f); \
  float eA_ = cjA*wA_, eB_ = cjA*wB_, fA_ = cjB*wA_, fB_ = cjB*wB_; \
  if (h0_ != 0.0f){ a0A0 += h0_*eA_; a0A1 += h0_*eB_; a0B0 += h0_*fA_; a0B1 += h0_*fB_; } \
  if (h1_ != 0.0f){ a1A0 += h1_*eA_; a1A1 += h1_*eB_; a1B0 += h1_*fA_; a1B1 += h1_*fB_; } \
  if (h2_ != 0.0f){ a2A0 += h2_*eA_; a2A1 += h2_*eB_; a2B0 += h2_*fA_; a2B1 += h2_*fB_; } \
  if (h3_ != 0.0f){ a3A0 += h3_*eA_; a3A1 += h3_*eB_; a3B0 += h3_*fA_; a3B1 += h3_*fB_; } \
}

#define HALF(IB) \
  _Pragma("unroll") \
  for (int ib=0; ib<32; ib+=4){ \
    f4 v0_ = LD1((IB)+ib+0); \
    f4 v1_ = LD1((IB)+ib+1); \
    f4 v2_ = LD1((IB)+ib+2); \
    f4 v3_ = LD1((IB)+ib+3); \
    BODY((IB)+ib+0, v0_); \
    BODY((IB)+ib+1, v1_); \
    BODY((IB)+ib+2, v2_); \
    BODY((IB)+ib+3, v3_); \
  }

__global__ __launch_bounds__(1024, 8) void k_pass1(const float* __restrict__ x,
                                                   float* __restrict__ dsums,
                                                   float* __restrict__ xbsums){
  __shared__ float xbL[64];
  __shared__ float bsL[64];
  int tid = threadIdx.x;
  int b = blockIdx.x;
  int mc  = b >> 1;
  int seg = b & 1;
  if (tid < 64){ xbL[tid]=0.f; bsL[tid]=0.f; }
  const float* xp = x + (size_t)mc * NVOX;
  int chunk = tid & 15;
  int j     = tid >> 4;
  float wqz0,wqz1,wqz2,wqz3;
  {
    int z0 = chunk*4;
    int lzc0 = (z0<8)?0:((z0>=56)?3:((z0-8)>>4));
    wqz0 = (z0  <8||z0  >=56)?0.0f:((z0+0.5f)*0.0625f-0.5f-(float)lzc0);
    wqz1 = (z0+1<8||z0+1>=56)?0.0f:((z0+1.5f)*0.0625f-0.5f-(float)lzc0);
    wqz2 = (z0+2<8||z0+2>=56)?0.0f:((z0+2.5f)*0.0625f-0.5f-(float)lzc0);
    wqz3 = (z0+3<8||z0+3>=56)?0.0f:((z0+3.5f)*0.0625f-0.5f-(float)lzc0);
  }
  int lzc = (chunk*4<8)?0:((chunk*4>=56)?3:((chunk*4-8)>>4));
  float cjA, cjB; int lj;
  {
    float cj = fminf(fmaxf((j+0.5f)*0.0625f-0.5f, 0.0f), 3.0f);
    lj = (int)cj; float wj = cj - (float)lj;
    cjA = 1.0f - wj; cjB = wj;
  }
  int jq = j >> 4, kq = chunk >> 2;

  float a0A0=0.f,a0A1=0.f,a0B0=0.f,a0B1=0.f;
  float a1A0=0.f,a1A1=0.f,a1B0=0.f,a1B1=0.f;
  float a2A0=0.f,a2A1=0.f,a2B0=0.f,a2B1=0.f;
  float a3A0=0.f,a3A1=0.f,a3B0=0.f,a3B1=0.f;
  float b0=0.f,b1=0.f,b2=0.f,b3=0.f;

  if (seg == 0){ HALF(0) } else { HALF(32) }

  __syncthreads();
  {
    int p00 = lj*4 + lzc;
    atomicAdd(&xbL[ 0 + p00], a0A0);
    atomicAdd(&xbL[16 + p00], a1A0);
    atomicAdd(&xbL[32 + p00], a2A0);
    atomicAdd(&xbL[48 + p00], a3A0);
    if (lzc < 3){
      atomicAdd(&xbL[ 0 + p00+1], a0A1);
      atomicAdd(&xbL[16 + p00+1], a1A1);
      atomicAdd(&xbL[32 + p00+1], a2A1);
      atomicAdd(&xbL[48 + p00+1], a3A1);
    }
    if (lj < 3){
      atomicAdd(&xbL[ 0 + p00+4], a0B0);
      atomicAdd(&xbL[16 + p00+4], a1B0);
      atomicAdd(&xbL[32 + p00+4], a2B0);
      atomicAdd(&xbL[48 + p00+4], a3B0);
      if (lzc < 3){
        atomicAdd(&xbL[ 0 + p00+5], a0B1);
        atomicAdd(&xbL[16 + p00+5], a1B1);
        atomicAdd(&xbL[32 + p00+5], a2B1);
        atomicAdd(&xbL[48 + p00+5], a3B1);
      }
    }
  }
  atomicAdd(&bsL[0*16 + jq*4 + kq], b0);
  atomicAdd(&bsL[1*16 + jq*4 + kq], b1);
  atomicAdd(&bsL[2*16 + jq*4 + kq], b2);
  atomicAdd(&bsL[3*16 + jq*4 + kq], b3);
  __syncthreads();
  if (tid < 64){
    atomicAdd(&xbsums[(size_t)mc*64 + tid], xbL[tid]);
    atomicAdd(&dsums [(size_t)mc*64 + tid], bsL[tid]);
  }
}

// ---------------- pass 2: all tiny MLPs (single block) + wf->bf16 conversion ----------------
__global__ __launch_bounds__(256) void k_pass2(
    const float* __restrict__ dsums, const float* __restrict__ xbsums,
    const float* __restrict__ wq1, const float* __restrict__ bq1,
    const float* __restrict__ wq2, const float* __restrict__ bq2,
    const float* __restrict__ wa1, const float* __restrict__ ba1,
    const float* __restrict__ wa2, const float* __restrict__ ba2,
    const float* __restrict__ wf,  const float* __restrict__ bfv,
    const float* __restrict__ wg1, const float* __restrict__ bg1,
    const float* __restrict__ wg2, const float* __restrict__ bg2,
    float* __restrict__ wsa, float* __restrict__ wsgate,
    float* __restrict__ wsqw, float* __restrict__ wsinv,
    unsigned short* __restrict__ wfb,
    float* __restrict__ outp)
{
  __shared__ float sGap[256];
  __shared__ float sA[256];
  __shared__ float sCm[256];
  __shared__ float sG[256];
  __shared__ float sGG[16];
  __shared__ float sQw[4];
  int tid = threadIdx.x;
  int m = tid>>6, c = tid&63;
  for (int t = tid; t < 4096; t += 256) wfb[t] = f2b(wf[t]);
  {
    float s=0.f;
    const float* dp = dsums + (size_t)tid*64;
    for (int p=0;p<64;++p) s += dp[p];
    sGap[tid] = s * (1.0f/262144.0f);
  }
  {
    int p = c;
    float h0=0,h1=0,h2=0,h3=0;
    for (int cc=0; cc<64; ++cc){
      float dm = dsums[((size_t)(m*64+cc))*64+p] * (1.0f/4096.0f);
      h0 += dm * wa1[0*64+cc];
      h1 += dm * wa1[1*64+cc];
      h2 += dm * wa1[2*64+cc];
      h3 += dm * wa1[3*64+cc];
    }
    h0 = fmaxf(h0 + ba1[0], 0.f);
    h1 = fmaxf(h1 + ba1[1], 0.f);
    h2 = fmaxf(h2 + ba1[2], 0.f);
    h3 = fmaxf(h3 + ba1[3], 0.f);
    float s = h0*wa2[0] + h1*wa2[1] + h2*wa2[2] + h3*wa2[3] + ba2[0];
    float aa = sigm(s);
    sA[tid] = aa;
    wsa[tid] = aa;
  }
  __syncthreads();
  if (tid < 4){
    int mm = tid;
    float q0=0,q1=0,q2=0,q3=0;
    for (int cc=0; cc<64; ++cc){
      float g = sGap[mm*64+cc];
      q0 += g*wq1[0*64+cc];
      q1 += g*wq1[1*64+cc];
      q2 += g*wq1[2*64+cc];
      q3 += g*wq1[3*64+cc];
    }
    q0 = fmaxf(q0+bq1[0],0.f); q1 = fmaxf(q1+bq1[1],0.f);
    q2 = fmaxf(q2+bq1[2],0.f); q3 = fmaxf(q3+bq1[3],0.f);
    float s0 = sigm(q0*wq2[0]+q1*wq2[1]+q2*wq2[2]+q3*wq2[3]+bq2[0]);
    float s1 = sigm(q0*wq2[4]+q1*wq2[5]+q2*wq2[6]+q3*wq2[7]+bq2[1]);
    sQw[mm] = 0.5f*(s0+s1);
    outp[MB_TOT + mm]     = s0;  // boundary
    outp[MB_TOT + 4 + mm] = s1;  // semantic
  }
  __syncthreads();
  float qw_m = sQw[m];
  float T = sQw[0]+sQw[1]+sQw[2]+sQw[3];
  float inv_m = 1.0f/(T - qw_m);
  if (tid < 4){ wsqw[tid] = sQw[tid]; wsinv[tid] = 1.0f/(T - sQw[tid]); }
  {
    const float* xbp = xbsums + (size_t)tid*64;
    float s=0.f;
    for (int p=0;p<64;++p) s += sA[m*64+p]*xbp[p];
    sCm[tid] = qw_m * s * (1.0f/262144.0f);
  }
  __syncthreads();
  {
    int dd = c;
    float acc=0.f;
    for (int cc=0; cc<64; ++cc){
      float Sm = sCm[0*64+cc]+sCm[1*64+cc]+sCm[2*64+cc]+sCm[3*64+cc];
      float em = (Sm - sCm[m*64+cc]) * inv_m;
      acc += em * wf[dd*64+cc];
    }
    sG[tid] = acc + bfv[dd];
  }
  __syncthreads();
  if (tid < 16){
    int mm = tid>>2, k = tid&3;
    float acc=0.f;
    for (int dd=0; dd<64; ++dd) acc += sG[mm*64+dd]*wg1[k*64+dd];
    sGG[tid] = fmaxf(acc + bg1[k], 0.f);
  }
  __syncthreads();
  {
    float s = sGG[m*4+0]*wg2[c*4+0] + sGG[m*4+1]*wg2[c*4+1]
            + sGG[m*4+2]*wg2[c*4+2] + sGG[m*4+3]*wg2[c*4+3] + bg2[c];
    wsgate[tid] = sigm(s);
  }
}

// ---------------- pass 3: coalesced staging + MFMA + coalesced transposed store ----------------
__global__ __launch_bounds__(256) void k_pass3(
    const float* __restrict__ x, const unsigned short* __restrict__ wfb,
    const float* __restrict__ bfv,
    const float* __restrict__ wsa, const float* __restrict__ wsgate,
    const float* __restrict__ wsqw, const float* __restrict__ wsinv,
    float* __restrict__ outp)
{
  __shared__ unsigned int xt[4][32][68];     // [m][cc-pair][vox] bf16 pairs; 16B-aligned rows
  __shared__ unsigned int fusedT[64][34];    // [dd][vox-pair] bf16 pairs
  __shared__ float aCell[4][64];
  __shared__ float gateL[4][64];
  __shared__ __align__(16) float auq[4][64];
  __shared__ float bfL[64];
  __shared__ float A2[4][4];
  int tid = threadIdx.x;
  int b = 4095 - (int)blockIdx.x;     // reversed tile order (L3 reuse from pass1)
  int i = b >> 6, j = b & 63;
  size_t V0 = (size_t)b * 64;
  int w    = tid >> 6;
  int lane = tid & 63;
  int ks   = lane >> 4;
  int r    = lane & 15;
  int vox16 = w << 4;

  const float* xw = x + (size_t)(w*64)*NVOX + V0 + r*4;
  f4 v[16];
#pragma unroll
  for (int rr=0; rr<16; ++rr){
    int cc = ks*16 + rr;
    v[rr] = *reinterpret_cast<const f4*>(xw + (size_t)cc*NVOX);
  }
  aCell[w][lane] = wsa[tid];
  gateL[w][lane] = wsgate[tid];
  if (tid < 64) bfL[tid] = bfv[tid];
#pragma unroll
  for (int rr=0; rr<16; rr+=2){
    u4v pk;
#pragma unroll
    for (int q=0;q<4;++q) pk[q] = cvtpk(v[rr][q], v[rr+1][q]);
    *reinterpret_cast<u4v*>(&xt[w][ks*8 + (rr>>1)][r*4]) = pk;
  }
  __syncthreads();

  if (tid < 16){
    int mm = tid>>2, pz = tid&3;
    float ci = fminf(fmaxf((i+0.5f)*0.0625f-0.5f,0.f),3.f);
    int li=(int)ci; float wi=ci-(float)li; int hiI=li<3?li+1:3;
    float cj = fminf(fmaxf((j+0.5f)*0.0625f-0.5f,0.f),3.f);
    int lj=(int)cj; float wj=cj-(float)lj; int hj=lj<3?lj+1:3;
    A2[mm][pz] = (1.f-wi)*((1.f-wj)*aCell[mm][li*16+lj*4+pz] + wj*aCell[mm][li*16+hj*4+pz])
               + wi*((1.f-wj)*aCell[mm][hiI*16+lj*4+pz] + wj*aCell[mm][hiI*16+hj*4+pz]);
  }
  __syncthreads();
  {
    int mm = tid>>6, z = tid&63;
    float cz = fminf(fmaxf((z+0.5f)*0.0625f-0.5f,0.f),3.f);
    int lz=(int)cz; float wzf=cz-(float)lz; int hz=lz<3?lz+1:3;
    auq[mm][z] = ((1.f-wzf)*A2[mm][lz] + wzf*A2[mm][hz]) * wsqw[mm];
  }
  __syncthreads();

  s8v bfr[4][2];
#pragma unroll
  for (int t=0;t<4;++t)
#pragma unroll
    for (int kk=0;kk<2;++kk)
      bfr[t][kk] = *reinterpret_cast<const s8v*>(&wfb[(t*16 + r)*64 + kk*32 + ks*8]);

  f4 acc[4][4];
#pragma unroll
  for (int mm=0;mm<4;++mm)
#pragma unroll
    for (int t=0;t<4;++t) acc[mm][t] = f4{0.f,0.f,0.f,0.f};

#pragma unroll
  for (int mm=0;mm<4;++mm){
    union { unsigned int u[4]; s8v s; } A0, A1;
#pragma unroll
    for (int q=0;q<4;++q){
      A0.u[q] = xt[mm][ks*4+q][vox16+r];
      A1.u[q] = xt[mm][16+ks*4+q][vox16+r];
    }
#pragma unroll
    for (int t=0;t<4;++t){
      acc[mm][t] = __builtin_amdgcn_mfma_f32_16x16x32_bf16(A0.s, bfr[t][0], acc[mm][t], 0,0,0);
      acc[mm][t] = __builtin_amdgcn_mfma_f32_16x16x32_bf16(A1.s, bfr[t][1], acc[mm][t], 0,0,0);
    }
  }

  f4 aq[4]; float invv[4];
#pragma unroll
  for (int mm=0;mm<4;++mm){
    aq[mm]  = *reinterpret_cast<const f4*>(&auq[mm][vox16 + 4*ks]);
    invv[mm] = wsinv[mm];
  }
  f4 FS[4];
#pragma unroll
  for (int t=0;t<4;++t){
    FS[t] = f4{0.f,0.f,0.f,0.f};
#pragma unroll
    for (int mm=0;mm<4;++mm)
#pragma unroll
      for (int q=0;q<4;++q) FS[t][q] += aq[mm][q]*acc[mm][t][q];
  }

  int g4 = tid >> 4;
  int r4l = tid & 15;
#pragma unroll
  for (int mm=0;mm<4;++mm){
#pragma unroll
    for (int t=0;t<4;++t){
      int dd = t*16 + r;
      float bfvv = bfL[dd];
      float f0 = (FS[t][0] - aq[mm][0]*acc[mm][t][0])*invv[mm] + bfvv;
      float f1 = (FS[t][1] - aq[mm][1]*acc[mm][t][1])*invv[mm] + bfvv;
      float f2 = (FS[t][2] - aq[mm][2]*acc[mm][t][2])*invv[mm] + bfvv;
      float f3 = (FS[t][3] - aq[mm][3]*acc[mm][t][3])*invv[mm] + bfvv;
      u2v pk2;
      pk2.x = cvtpk(f0, f1);
      pk2.y = cvtpk(f2, f3);
      *reinterpret_cast<u2v*>(&fusedT[dd][(vox16 + ks*4)>>1]) = pk2;
    }
    __syncthreads();
#pragma unroll
    for (int rr=0; rr<4; ++rr){
      int dd = rr*16 + g4;
      float g = gateL[mm][dd];
      u4v xu = *reinterpret_cast<const u4v*>(&xt[mm][dd>>1][r4l*4]);
      u2v fu = *reinterpret_cast<const u2v*>(&fusedT[dd][r4l*2]);
      f4 o;
      float x0 = (dd&1) ? bh(xu[0]) : bl(xu[0]);
      float x1 = (dd&1) ? bh(xu[1]) : bl(xu[1]);
      float x2 = (dd&1) ? bh(xu[2]) : bl(xu[2]);
      float x3 = (dd&1) ? bh(xu[3]) : bl(xu[3]);
      o[0] = x0 + g*bl(fu.x);
      o[1] = x1 + g*bh(fu.x);
      o[2] = x2 + g*bl(fu.y);
      o[3] = x3 + g*bh(fu.y);
      *reinterpret_cast<f4*>(outp + (size_t)(mm*64+dd)*NVOX + V0 + r4l*4) = o;
    }
    __syncthreads();
  }
}

extern "C" void kernel_launch(void* const* d_in, const int* in_sizes, int n_in,
                              void* d_out, int out_size, void* d_ws, size_t ws_size,
                              hipStream_t stream){
  const float* x   = (const float*)d_in[0];
  const float* wq1 = (const float*)d_in[1];
  const float* bq1 = (const float*)d_in[2];
  const float* wq2 = (const float*)d_in[3];
  const float* bq2 = (const float*)d_in[4];
  const float* wa1 = (const float*)d_in[5];
  const float* ba1 = (const float*)d_in[6];
  const float* wa2 = (const float*)d_in[7];
  const float* ba2 = (const float*)d_in[8];
  const float* wf  = (const float*)d_in[9];
  const float* bfv = (const float*)d_in[10];
  const float* wg1 = (const float*)d_in[11];
  const float* bg1 = (const float*)d_in[12];
  const float* wg2 = (const float*)d_in[13];
  const float* bg2 = (const float*)d_in[14];
  float* outp = (float*)d_out;
  float* w = (float*)d_ws;
  float* dsums  = w;            // 16384 floats
  float* xbsums = w + 16384;    // 16384 floats
  float* wsa    = w + 32768;    // 256
  float* wsgate = w + 33024;    // 256
  float* wsqw   = w + 33280;    // 4
  float* wsinv  = w + 33284;    // 4
  unsigned short* wfb = (unsigned short*)(w + 33288);  // 4096 bf16
  hipMemsetAsync(w, 0, 32768*sizeof(float), stream);
  hipLaunchKernelGGL(k_pass1, dim3(512), dim3(1024), 0, stream, x, dsums, xbsums);
  hipLaunchKernelGGL(k_pass2, dim3(1), dim3(256), 0, stream, dsums, xbsums,
                     wq1,bq1,wq2,bq2,wa1,ba1,wa2,ba2,wf,bfv,wg1,bg1,wg2,bg2,
                     wsa, wsgate, wsqw, wsinv, wfb, outp);
  hipLaunchKernelGGL(k_pass3, dim3(4096), dim3(256), 0, stream, x, wfb, bfv,
                     wsa, wsgate, wsqw, wsinv, outp);
}

// Round 9
// 246.450 us; speedup vs baseline: 1.4474x; 1.4474x over previous
//
#include <hip/hip_runtime.h>
#include <math.h>

typedef __attribute__((ext_vector_type(4))) float f4;
typedef __attribute__((ext_vector_type(8))) short s8v;   // bf16x8 MFMA fragment
typedef __attribute__((ext_vector_type(4))) unsigned int u4v;
typedef __attribute__((ext_vector_type(2))) unsigned int u2v;

#define NVOX 262144        // 64^3
#define MB_TOT 67108864    // 4*64*NVOX

__device__ __forceinline__ float sigm(float x){ return 1.0f/(1.0f+expf(-x)); }
__device__ __forceinline__ unsigned short f2b(float f){
  unsigned x = __float_as_uint(f);
  return (unsigned short)((x + 0x7fffu + ((x>>16)&1u)) >> 16);
}
__device__ __forceinline__ unsigned cvtpk(float lo, float hi){
  unsigned r;
  asm("v_cvt_pk_bf16_f32 %0, %1, %2" : "=v"(r) : "v"(lo), "v"(hi));
  return r;
}
__device__ __forceinline__ float bl(unsigned u){ return __uint_as_float(u<<16); }
__device__ __forceinline__ float bh(unsigned u){ return __uint_as_float(u & 0xffff0000u); }

// ---------------- pass 1: 1024 blocks x 512 threads, explicit load batches, no forced occupancy ----
// block = (mc = b>>2, seg = b&3 -> i in [seg*16, seg*16+16)).
// thread: chunk = tid&15 (z = chunk*4..+3), jbase = tid>>4 (0..31); j = jbase + jh*32.
// Per j-half: accumulate 16 i-rows into 17 named scalars (batch-4 explicit loads), then
// LDS-atomic merge. Small blocks avoid the 1024-thread residency cliff; VGPR lands free.

#define LD(I,J) (*reinterpret_cast<const f4*>(xp + (size_t)((I)*64 + (J))*64 + chunk*4))

#define BODY(I, V) { \
  float s_ = ((V).x+(V).y)+((V).z+(V).w); \
  float wB_ = (V).x*wqz0 + (V).y*wqz1 + (V).z*wqz2 + (V).w*wqz3; \
  float wA_ = s_ - wB_; \
  bacc += s_; \
  const int   li_  = ((I)<8)?0:(((I)>=56)?3:(((I)-8)>>4)); \
  const float wi_  = ((I)<8||(I)>=56)?0.0f:(((I)+0.5f)*0.0625f-0.5f-(float)li_); \
  const float h0_ = (li_==0)?(1.0f-wi_):0.0f; \
  const float h1_ = (li_==1)?(1.0f-wi_):((li_==0)?wi_:0.0f); \
  const float h2_ = (li_==2)?(1.0f-wi_):((li_==1)?wi_:0.0f); \
  const float h3_ = (li_==3)?(1.0f-wi_):((li_==2)?wi_:0.0f); \
  float eA_ = cjA*wA_, eB_ = cjA*wB_, fA_ = cjB*wA_, fB_ = cjB*wB_; \
  if (h0_ != 0.0f){ a0A0 += h0_*eA_; a0A1 += h0_*eB_; a0B0 += h0_*fA_; a0B1 += h0_*fB_; } \
  if (h1_ != 0.0f){ a1A0 += h1_*eA_; a1A1 += h1_*eB_; a1B0 += h1_*fA_; a1B1 += h1_*fB_; } \
  if (h2_ != 0.0f){ a2A0 += h2_*eA_; a2A1 += h2_*eB_; a2B0 += h2_*fA_; a2B1 += h2_*fB_; } \
  if (h3_ != 0.0f){ a3A0 += h3_*eA_; a3A1 += h3_*eB_; a3B0 += h3_*fA_; a3B1 += h3_*fB_; } \
}

#define SEG16(I0) \
  _Pragma("unroll") \
  for (int ib=0; ib<16; ib+=4){ \
    f4 v0_ = LD((I0)+ib+0, j); \
    f4 v1_ = LD((I0)+ib+1, j); \
    f4 v2_ = LD((I0)+ib+2, j); \
    f4 v3_ = LD((I0)+ib+3, j); \
    BODY((I0)+ib+0, v0_); \
    BODY((I0)+ib+1, v1_); \
    BODY((I0)+ib+2, v2_); \
    BODY((I0)+ib+3, v3_); \
  }

__global__ __launch_bounds__(512) void k_pass1(const float* __restrict__ x,
                                               float* __restrict__ dsums,
                                               float* __restrict__ xbsums){
  __shared__ float xbL[64];
  __shared__ float bsL[64];
  int tid = threadIdx.x;
  int b = blockIdx.x;
  int mc  = b >> 2;
  int seg = b & 3;
  if (tid < 64){ xbL[tid]=0.f; bsL[tid]=0.f; }
  __syncthreads();
  const float* xp = x + (size_t)mc * NVOX;
  int chunk = tid & 15;
  int jbase = tid >> 4;       // 0..31
  float wqz0,wqz1,wqz2,wqz3;
  {
    int z0 = chunk*4;
    int lzc0 = (z0<8)?0:((z0>=56)?3:((z0-8)>>4));
    wqz0 = (z0  <8||z0  >=56)?0.0f:((z0+0.5f)*0.0625f-0.5f-(float)lzc0);
    wqz1 = (z0+1<8||z0+1>=56)?0.0f:((z0+1.5f)*0.0625f-0.5f-(float)lzc0);
    wqz2 = (z0+2<8||z0+2>=56)?0.0f:((z0+2.5f)*0.0625f-0.5f-(float)lzc0);
    wqz3 = (z0+3<8||z0+3>=56)?0.0f:((z0+3.5f)*0.0625f-0.5f-(float)lzc0);
  }
  int lzc = (chunk*4<8)?0:((chunk*4>=56)?3:((chunk*4-8)>>4));
  int kq = chunk >> 2;

#pragma unroll
  for (int jh=0; jh<2; ++jh){
    int j = jbase + jh*32;
    float cjA, cjB; int lj;
    {
      float cj = fminf(fmaxf((j+0.5f)*0.0625f-0.5f, 0.0f), 3.0f);
      lj = (int)cj; float wj = cj - (float)lj;
      cjA = 1.0f - wj; cjB = wj;
    }
    float a0A0=0.f,a0A1=0.f,a0B0=0.f,a0B1=0.f;
    float a1A0=0.f,a1A1=0.f,a1B0=0.f,a1B1=0.f;
    float a2A0=0.f,a2A1=0.f,a2B0=0.f,a2B1=0.f;
    float a3A0=0.f,a3A1=0.f,a3B0=0.f,a3B1=0.f;
    float bacc=0.f;

    if      (seg == 0){ SEG16(0)  }
    else if (seg == 1){ SEG16(16) }
    else if (seg == 2){ SEG16(32) }
    else              { SEG16(48) }

    // merge this j-half into LDS
    {
      int p00 = lj*4 + lzc;
      atomicAdd(&xbL[ 0 + p00], a0A0);
      atomicAdd(&xbL[16 + p00], a1A0);
      atomicAdd(&xbL[32 + p00], a2A0);
      atomicAdd(&xbL[48 + p00], a3A0);
      if (lzc < 3){
        atomicAdd(&xbL[ 0 + p00+1], a0A1);
        atomicAdd(&xbL[16 + p00+1], a1A1);
        atomicAdd(&xbL[32 + p00+1], a2A1);
        atomicAdd(&xbL[48 + p00+1], a3A1);
      }
      if (lj < 3){
        atomicAdd(&xbL[ 0 + p00+4], a0B0);
        atomicAdd(&xbL[16 + p00+4], a1B0);
        atomicAdd(&xbL[32 + p00+4], a2B0);
        atomicAdd(&xbL[48 + p00+4], a3B0);
        if (lzc < 3){
          atomicAdd(&xbL[ 0 + p00+5], a0B1);
          atomicAdd(&xbL[16 + p00+5], a1B1);
          atomicAdd(&xbL[32 + p00+5], a2B1);
          atomicAdd(&xbL[48 + p00+5], a3B1);
        }
      }
      atomicAdd(&bsL[seg*16 + (j>>4)*4 + kq], bacc);
    }
  }
  __syncthreads();
  if (tid < 64){
    atomicAdd(&xbsums[(size_t)mc*64 + tid], xbL[tid]);
    atomicAdd(&dsums [(size_t)mc*64 + tid], bsL[tid]);
  }
}

// ---------------- pass 2: all tiny MLPs (single block) + wf->bf16 conversion ----------------
__global__ __launch_bounds__(256) void k_pass2(
    const float* __restrict__ dsums, const float* __restrict__ xbsums,
    const float* __restrict__ wq1, const float* __restrict__ bq1,
    const float* __restrict__ wq2, const float* __restrict__ bq2,
    const float* __restrict__ wa1, const float* __restrict__ ba1,
    const float* __restrict__ wa2, const float* __restrict__ ba2,
    const float* __restrict__ wf,  const float* __restrict__ bfv,
    const float* __restrict__ wg1, const float* __restrict__ bg1,
    const float* __restrict__ wg2, const float* __restrict__ bg2,
    float* __restrict__ wsa, float* __restrict__ wsgate,
    float* __restrict__ wsqw, float* __restrict__ wsinv,
    unsigned short* __restrict__ wfb,
    float* __restrict__ outp)
{
  __shared__ float sGap[256];
  __shared__ float sA[256];
  __shared__ float sCm[256];
  __shared__ float sG[256];
  __shared__ float sGG[16];
  __shared__ float sQw[4];
  int tid = threadIdx.x;
  int m = tid>>6, c = tid&63;
  for (int t = tid; t < 4096; t += 256) wfb[t] = f2b(wf[t]);
  {
    float s=0.f;
    const float* dp = dsums + (size_t)tid*64;
    for (int p=0;p<64;++p) s += dp[p];
    sGap[tid] = s * (1.0f/262144.0f);
  }
  {
    int p = c;
    float h0=0,h1=0,h2=0,h3=0;
    for (int cc=0; cc<64; ++cc){
      float dm = dsums[((size_t)(m*64+cc))*64+p] * (1.0f/4096.0f);
      h0 += dm * wa1[0*64+cc];
      h1 += dm * wa1[1*64+cc];
      h2 += dm * wa1[2*64+cc];
      h3 += dm * wa1[3*64+cc];
    }
    h0 = fmaxf(h0 + ba1[0], 0.f);
    h1 = fmaxf(h1 + ba1[1], 0.f);
    h2 = fmaxf(h2 + ba1[2], 0.f);
    h3 = fmaxf(h3 + ba1[3], 0.f);
    float s = h0*wa2[0] + h1*wa2[1] + h2*wa2[2] + h3*wa2[3] + ba2[0];
    float aa = sigm(s);
    sA[tid] = aa;
    wsa[tid] = aa;
  }
  __syncthreads();
  if (tid < 4){
    int mm = tid;
    float q0=0,q1=0,q2=0,q3=0;
    for (int cc=0; cc<64; ++cc){
      float g = sGap[mm*64+cc];
      q0 += g*wq1[0*64+cc];
      q1 += g*wq1[1*64+cc];
      q2 += g*wq1[2*64+cc];
      q3 += g*wq1[3*64+cc];
    }
    q0 = fmaxf(q0+bq1[0],0.f); q1 = fmaxf(q1+bq1[1],0.f);
    q2 = fmaxf(q2+bq1[2],0.f); q3 = fmaxf(q3+bq1[3],0.f);
    float s0 = sigm(q0*wq2[0]+q1*wq2[1]+q2*wq2[2]+q3*wq2[3]+bq2[0]);
    float s1 = sigm(q0*wq2[4]+q1*wq2[5]+q2*wq2[6]+q3*wq2[7]+bq2[1]);
    sQw[mm] = 0.5f*(s0+s1);
    outp[MB_TOT + mm]     = s0;  // boundary
    outp[MB_TOT + 4 + mm] = s1;  // semantic
  }
  __syncthreads();
  float qw_m = sQw[m];
  float T = sQw[0]+sQw[1]+sQw[2]+sQw[3];
  float inv_m = 1.0f/(T - qw_m);
  if (tid < 4){ wsqw[tid] = sQw[tid]; wsinv[tid] = 1.0f/(T - sQw[tid]); }
  {
    const float* xbp = xbsums + (size_t)tid*64;
    float s=0.f;
    for (int p=0;p<64;++p) s += sA[m*64+p]*xbp[p];
    sCm[tid] = qw_m * s * (1.0f/262144.0f);
  }
  __syncthreads();
  {
    int dd = c;
    float acc=0.f;
    for (int cc=0; cc<64; ++cc){
      float Sm = sCm[0*64+cc]+sCm[1*64+cc]+sCm[2*64+cc]+sCm[3*64+cc];
      float em = (Sm - sCm[m*64+cc]) * inv_m;
      acc += em * wf[dd*64+cc];
    }
    sG[tid] = acc + bfv[dd];
  }
  __syncthreads();
  if (tid < 16){
    int mm = tid>>2, k = tid&3;
    float acc=0.f;
    for (int dd=0; dd<64; ++dd) acc += sG[mm*64+dd]*wg1[k*64+dd];
    sGG[tid] = fmaxf(acc + bg1[k], 0.f);
  }
  __syncthreads();
  {
    float s = sGG[m*4+0]*wg2[c*4+0] + sGG[m*4+1]*wg2[c*4+1]
            + sGG[m*4+2]*wg2[c*4+2] + sGG[m*4+3]*wg2[c*4+3] + bg2[c];
    wsgate[tid] = sigm(s);
  }
}

// ---------------- pass 3: coalesced staging + MFMA + coalesced transposed store ----------------
__global__ __launch_bounds__(256) void k_pass3(
    const float* __restrict__ x, const unsigned short* __restrict__ wfb,
    const float* __restrict__ bfv,
    const float* __restrict__ wsa, const float* __restrict__ wsgate,
    const float* __restrict__ wsqw, const float* __restrict__ wsinv,
    float* __restrict__ outp)
{
  __shared__ unsigned int xt[4][32][68];     // [m][cc-pair][vox] bf16 pairs; 16B-aligned rows
  __shared__ unsigned int fusedT[64][34];    // [dd][vox-pair] bf16 pairs
  __shared__ float aCell[4][64];
  __shared__ float gateL[4][64];
  __shared__ __align__(16) float auq[4][64];
  __shared__ float bfL[64];
  __shared__ float A2[4][4];
  int tid = threadIdx.x;
  int b = 4095 - (int)blockIdx.x;     // reversed tile order (L3 reuse from pass1)
  int i = b >> 6, j = b & 63;
  size_t V0 = (size_t)b * 64;
  int w    = tid >> 6;
  int lane = tid & 63;
  int ks   = lane >> 4;
  int r    = lane & 15;
  int vox16 = w << 4;

  const float* xw = x + (size_t)(w*64)*NVOX + V0 + r*4;
  f4 v[16];
#pragma unroll
  for (int rr=0; rr<16; ++rr){
    int cc = ks*16 + rr;
    v[rr] = *reinterpret_cast<const f4*>(xw + (size_t)cc*NVOX);
  }
  aCell[w][lane] = wsa[tid];
  gateL[w][lane] = wsgate[tid];
  if (tid < 64) bfL[tid] = bfv[tid];
#pragma unroll
  for (int rr=0; rr<16; rr+=2){
    u4v pk;
#pragma unroll
    for (int q=0;q<4;++q) pk[q] = cvtpk(v[rr][q], v[rr+1][q]);
    *reinterpret_cast<u4v*>(&xt[w][ks*8 + (rr>>1)][r*4]) = pk;
  }
  __syncthreads();

  if (tid < 16){
    int mm = tid>>2, pz = tid&3;
    float ci = fminf(fmaxf((i+0.5f)*0.0625f-0.5f,0.f),3.f);
    int li=(int)ci; float wi=ci-(float)li; int hiI=li<3?li+1:3;
    float cj = fminf(fmaxf((j+0.5f)*0.0625f-0.5f,0.f),3.f);
    int lj=(int)cj; float wj=cj-(float)lj; int hj=lj<3?lj+1:3;
    A2[mm][pz] = (1.f-wi)*((1.f-wj)*aCell[mm][li*16+lj*4+pz] + wj*aCell[mm][li*16+hj*4+pz])
               + wi*((1.f-wj)*aCell[mm][hiI*16+lj*4+pz] + wj*aCell[mm][hiI*16+hj*4+pz]);
  }
  __syncthreads();
  {
    int mm = tid>>6, z = tid&63;
    float cz = fminf(fmaxf((z+0.5f)*0.0625f-0.5f,0.f),3.f);
    int lz=(int)cz; float wzf=cz-(float)lz; int hz=lz<3?lz+1:3;
    auq[mm][z] = ((1.f-wzf)*A2[mm][lz] + wzf*A2[mm][hz]) * wsqw[mm];
  }
  __syncthreads();

  s8v bfr[4][2];
#pragma unroll
  for (int t=0;t<4;++t)
#pragma unroll
    for (int kk=0;kk<2;++kk)
      bfr[t][kk] = *reinterpret_cast<const s8v*>(&wfb[(t*16 + r)*64 + kk*32 + ks*8]);

  f4 acc[4][4];
#pragma unroll
  for (int mm=0;mm<4;++mm)
#pragma unroll
    for (int t=0;t<4;++t) acc[mm][t] = f4{0.f,0.f,0.f,0.f};

#pragma unroll
  for (int mm=0;mm<4;++mm){
    union { unsigned int u[4]; s8v s; } A0, A1;
#pragma unroll
    for (int q=0;q<4;++q){
      A0.u[q] = xt[mm][ks*4+q][vox16+r];
      A1.u[q] = xt[mm][16+ks*4+q][vox16+r];
    }
#pragma unroll
    for (int t=0;t<4;++t){
      acc[mm][t] = __builtin_amdgcn_mfma_f32_16x16x32_bf16(A0.s, bfr[t][0], acc[mm][t], 0,0,0);
      acc[mm][t] = __builtin_amdgcn_mfma_f32_16x16x32_bf16(A1.s, bfr[t][1], acc[mm][t], 0,0,0);
    }
  }

  f4 aq[4]; float invv[4];
#pragma unroll
  for (int mm=0;mm<4;++mm){
    aq[mm]  = *reinterpret_cast<const f4*>(&auq[mm][vox16 + 4*ks]);
    invv[mm] = wsinv[mm];
  }
  f4 FS[4];
#pragma unroll
  for (int t=0;t<4;++t){
    FS[t] = f4{0.f,0.f,0.f,0.f};
#pragma unroll
    for (int mm=0;mm<4;++mm)
#pragma unroll
      for (int q=0;q<4;++q) FS[t][q] += aq[mm][q]*acc[mm][t][q];
  }

  int g4 = tid >> 4;
  int r4l = tid & 15;
#pragma unroll
  for (int mm=0;mm<4;++mm){
#pragma unroll
    for (int t=0;t<4;++t){
      int dd = t*16 + r;
      float bfvv = bfL[dd];
      float f0 = (FS[t][0] - aq[mm][0]*acc[mm][t][0])*invv[mm] + bfvv;
      float f1 = (FS[t][1] - aq[mm][1]*acc[mm][t][1])*invv[mm] + bfvv;
      float f2 = (FS[t][2] - aq[mm][2]*acc[mm][t][2])*invv[mm] + bfvv;
      float f3 = (FS[t][3] - aq[mm][3]*acc[mm][t][3])*invv[mm] + bfvv;
      u2v pk2;
      pk2.x = cvtpk(f0, f1);
      pk2.y = cvtpk(f2, f3);
      *reinterpret_cast<u2v*>(&fusedT[dd][(vox16 + ks*4)>>1]) = pk2;
    }
    __syncthreads();
#pragma unroll
    for (int rr=0; rr<4; ++rr){
      int dd = rr*16 + g4;
      float g = gateL[mm][dd];
      u4v xu = *reinterpret_cast<const u4v*>(&xt[mm][dd>>1][r4l*4]);
      u2v fu = *reinterpret_cast<const u2v*>(&fusedT[dd][r4l*2]);
      f4 o;
      float x0 = (dd&1) ? bh(xu[0]) : bl(xu[0]);
      float x1 = (dd&1) ? bh(xu[1]) : bl(xu[1]);
      float x2 = (dd&1) ? bh(xu[2]) : bl(xu[2]);
      float x3 = (dd&1) ? bh(xu[3]) : bl(xu[3]);
      o[0] = x0 + g*bl(fu.x);
      o[1] = x1 + g*bh(fu.x);
      o[2] = x2 + g*bl(fu.y);
      o[3] = x3 + g*bh(fu.y);
      *reinterpret_cast<f4*>(outp + (size_t)(mm*64+dd)*NVOX + V0 + r4l*4) = o;
    }
    __syncthreads();
  }
}

extern "C" void kernel_launch(void* const* d_in, const int* in_sizes, int n_in,
                              void* d_out, int out_size, void* d_ws, size_t ws_size,
                              hipStream_t stream){
  const float* x   = (const float*)d_in[0];
  const float* wq1 = (const float*)d_in[1];
  const float* bq1 = (const float*)d_in[2];
  const float* wq2 = (const float*)d_in[3];
  const float* bq2 = (const float*)d_in[4];
  const float* wa1 = (const float*)d_in[5];
  const float* ba1 = (const float*)d_in[6];
  const float* wa2 = (const float*)d_in[7];
  const float* ba2 = (const float*)d_in[8];
  const float* wf  = (const float*)d_in[9];
  const float* bfv = (const float*)d_in[10];
  const float* wg1 = (const float*)d_in[11];
  const float* bg1 = (const float*)d_in[12];
  const float* wg2 = (const float*)d_in[13];
  const float* bg2 = (const float*)d_in[14];
  float* outp = (float*)d_out;
  float* w = (float*)d_ws;
  float* dsums  = w;            // 16384 floats
  float* xbsums = w + 16384;    // 16384 floats
  float* wsa    = w + 32768;    // 256
  float* wsgate = w + 33024;    // 256
  float* wsqw   = w + 33280;    // 4
  float* wsinv  = w + 33284;    // 4
  unsigned short* wfb = (unsigned short*)(w + 33288);  // 4096 bf16
  hipMemsetAsync(w, 0, 32768*sizeof(float), stream);
  hipLaunchKernelGGL(k_pass1, dim3(1024), dim3(512), 0, stream, x, dsums, xbsums);
  hipLaunchKernelGGL(k_pass2, dim3(1), dim3(256), 0, stream, dsums, xbsums,
                     wq1,bq1,wq2,bq2,wa1,ba1,wa2,ba2,wf,bfv,wg1,bg1,wg2,bg2,
                     wsa, wsgate, wsqw, wsinv, wfb, outp);
  hipLaunchKernelGGL(k_pass3, dim3(4096), dim3(256), 0, stream, x, wfb, bfv,
                     wsa, wsgate, wsqw, wsinv, outp);
}